// Round 3
// baseline (1064.256 us; speedup 1.0000x reference)
//
#include <hip/hip_runtime.h>
#include <hip/hip_bf16.h>

// SwinMLP block, fp32 in/out, bf16 MFMA internals.
// Pipeline:
//   1) cvt_t: w1 -> w1t (bf16, N x K), w2 -> w2t (bf16, N x K)
//   2) fused_pre: per-row LN1 + per-head 32x32 spatial matmul + residual -> x2 (fp32, stored in d_out)
//      + LN2(x2) -> y (bf16, ws)
//   3) gemm_bt<512,2048,GELU>: z = gelu(y @ w1 + b1)  (bf16, ws)
//   4) gemm_bt<2048,512,RES>:  d_out = x2 + z @ w2 + b2 (in-place residual on d_out)
//
// R1: baseline m97 structure       -> gemms 449+457 us, MfmaUtil 20%, FETCH 919 MB (XCD A-replication)
// R2: + T1 XCD swizzle             -> FETCH 358/122 MB but dur unchanged => latency-bound, not BW
// R3 (this): T3-minimum 2-phase double-buffered pipeline: STAGE(next) issued
//   BEFORE compute(cur), one barrier per K-step. Exposed global->LDS latency
//   now overlaps ~300cy of ds_read+MFMA. Static buffer indexing (rule #20).

typedef __bf16 bf16x8 __attribute__((ext_vector_type(8)));
typedef float f32x4 __attribute__((ext_vector_type(4)));

constexpr int CDIM = 512;
constexpr int HID = 2048;
constexpr int MROWS = 32 * 3136;  // 100352 = 784 * 128
constexpr float LN_EPS = 1e-5f;

static __device__ __forceinline__ float gelu_tanh(float x) {
  const float u = 0.7978845608028654f * fmaf(0.044715f * x * x, x, x);
  const float e = __expf(2.0f * u);
  return 0.5f * x * (2.0f - 2.0f / (e + 1.0f));
}

static __device__ __forceinline__ void load_lds16(const void* g, void* l) {
  // 16B per lane, LDS dest = wave-uniform base + lane*16 (linear)
  __builtin_amdgcn_global_load_lds((__attribute__((address_space(1))) void*)g,
                                   (__attribute__((address_space(3))) void*)l,
                                   16, 0, 0);
}

// ---------------- weight transpose + bf16 convert ----------------
template <int KD>
__global__ __launch_bounds__(256) void cvt_t(const float* __restrict__ src,
                                             __hip_bfloat16* __restrict__ dst,
                                             int ND) {
  const int i = blockIdx.x * 256 + threadIdx.x;
  const int n = i / KD;
  const int k = i - n * KD;
  dst[i] = __float2bfloat16(src[(size_t)k * ND + n]);
}

// ---------------- fused LN1 + spatial mix + residual + LN2 ----------------
__global__ __launch_bounds__(256) void fused_pre(
    const float* __restrict__ x, const float* __restrict__ g1,
    const float* __restrict__ b1, const float* __restrict__ wsp,
    const float* __restrict__ g2, const float* __restrict__ b2,
    float* __restrict__ x2out, __hip_bfloat16* __restrict__ yout) {
  __shared__ float lnbuf[CDIM];
  __shared__ float red[8];

  const int t = threadIdx.x;
  const int lane = t & 63;
  const int w = t >> 6;
  const int c0 = t, c1 = t + 256;
  const int hd0 = c0 >> 5, e0 = c0 & 31;
  const int hd1 = c1 >> 5, e1 = c1 & 31;

  float wc0[32], wc1[32];
#pragma unroll
  for (int d = 0; d < 32; ++d) {
    wc0[d] = wsp[(hd0 * 32 + d) * 32 + e0];
    wc1[d] = wsp[(hd1 * 32 + d) * 32 + e1];
  }
  const float g1v0 = g1[c0], g1v1 = g1[c1], b1v0 = b1[c0], b1v1 = b1[c1];
  const float g2v0 = g2[c0], g2v1 = g2[c1], b2v0 = b2[c0], b2v1 = b2[c1];

  for (int r = blockIdx.x; r < MROWS; r += gridDim.x) {
    const float* xr = x + (size_t)r * CDIM;
    const float xv0 = xr[c0], xv1 = xr[c1];

    float s = xv0 + xv1, ss = xv0 * xv0 + xv1 * xv1;
#pragma unroll
    for (int off = 32; off; off >>= 1) {
      s += __shfl_down(s, off);
      ss += __shfl_down(ss, off);
    }
    if (lane == 0) { red[w * 2] = s; red[w * 2 + 1] = ss; }
    __syncthreads();  // B1
    s = red[0] + red[2] + red[4] + red[6];
    ss = red[1] + red[3] + red[5] + red[7];
    float mu = s * (1.0f / CDIM);
    float var = ss * (1.0f / CDIM) - mu * mu;
    float rs = rsqrtf(var + LN_EPS);
    lnbuf[c0] = (xv0 - mu) * rs * g1v0 + b1v0;
    lnbuf[c1] = (xv1 - mu) * rs * g1v1 + b1v1;
    __syncthreads();  // B2

    float h0 = 0.f, h1 = 0.f;
#pragma unroll
    for (int d = 0; d < 32; ++d) {
      h0 = fmaf(lnbuf[hd0 * 32 + d], wc0[d], h0);
      h1 = fmaf(lnbuf[hd1 * 32 + d], wc1[d], h1);
    }
    const float a0 = xv0 + h0, a1 = xv1 + h1;
    x2out[(size_t)r * CDIM + c0] = a0;
    x2out[(size_t)r * CDIM + c1] = a1;

    s = a0 + a1;
    ss = a0 * a0 + a1 * a1;
#pragma unroll
    for (int off = 32; off; off >>= 1) {
      s += __shfl_down(s, off);
      ss += __shfl_down(ss, off);
    }
    if (lane == 0) { red[w * 2] = s; red[w * 2 + 1] = ss; }
    __syncthreads();  // B3
    s = red[0] + red[2] + red[4] + red[6];
    ss = red[1] + red[3] + red[5] + red[7];
    mu = s * (1.0f / CDIM);
    var = ss * (1.0f / CDIM) - mu * mu;
    rs = rsqrtf(var + LN_EPS);
    yout[(size_t)r * CDIM + c0] = __float2bfloat16((a0 - mu) * rs * g2v0 + b2v0);
    yout[(size_t)r * CDIM + c1] = __float2bfloat16((a1 - mu) * rs * g2v1 + b2v1);
    __syncthreads();  // B4
  }
}

// ---------------- bf16 MFMA GEMM: C(MxN) = A(MxK) * Bt(NxK)^T ----------------
// 128x128 tile, 4 waves (2x2 of 64x64), BK=32, global_load_lds w16.
// 2-phase double-buffer (T3-min): prefetch tile kt+1 into buf^1 BEFORE
// computing tile kt from buf; single __syncthreads per K-step (its implicit
// vmcnt(0)+lgkmcnt(0) drain lands after compute covered the load latency).
template <int K, int N, bool GELU>
__global__ __launch_bounds__(256) void gemm_bt(
    const __hip_bfloat16* __restrict__ A, const __hip_bfloat16* __restrict__ Bt,
    const float* __restrict__ bias, __hip_bfloat16* __restrict__ zout,
    float* __restrict__ fout) {
  constexpr int NT = N / 128;
  constexpr int NKT = K / 32;  // 16 or 64, both even
  __shared__ __attribute__((aligned(16))) __hip_bfloat16 As[2][128 * 32];
  __shared__ __attribute__((aligned(16))) __hip_bfloat16 Bs[2][128 * 32];

  const int tid = threadIdx.x;
  const int lane = tid & 63;
  const int w = tid >> 6;
  const int wr = w >> 1, wc = w & 1;

  // T1: XCD-aware bijective swizzle (grid % 8 == 0 by construction)
  const int cpx = gridDim.x >> 3;
  const int bid = (blockIdx.x & 7) * cpx + (blockIdx.x >> 3);

  const int tm = bid / NT;  // consecutive logical bids share the A panel
  const int tn = bid - tm * NT;
  const size_t am0 = (size_t)tm * 128;
  const int bn0 = tn * 128;

  // staging: segment s in [0,512) of 16B; row = s>>2, k-sub = (s&3)*8
  const int s0 = w * 64 + lane;
  const int r0 = s0 >> 2, k0 = (s0 & 3) * 8;
  const int s1 = s0 + 256;
  const int r1 = s1 >> 2, k1 = (s1 & 3) * 8;
  const __hip_bfloat16* a0p = A + (am0 + r0) * K + k0;
  const __hip_bfloat16* a1p = A + (am0 + r1) * K + k1;
  const __hip_bfloat16* b0p = Bt + (size_t)(bn0 + r0) * K + k0;
  const __hip_bfloat16* b1p = Bt + (size_t)(bn0 + r1) * K + k1;
  const int ldsA0 = (w * 64) * 8;        // elements
  const int ldsA1 = (w * 64 + 256) * 8;

  f32x4 acc[4][4] = {};
  const int fr = lane & 15;
  const int kg = (lane >> 4) * 8;

#define STAGE(b, kb)                            \
  do {                                          \
    load_lds16(a0p + (kb), &As[b][ldsA0]);      \
    load_lds16(a1p + (kb), &As[b][ldsA1]);      \
    load_lds16(b0p + (kb), &Bs[b][ldsA0]);      \
    load_lds16(b1p + (kb), &Bs[b][ldsA1]);      \
  } while (0)

#define COMPUTE(b)                                                          \
  do {                                                                      \
    bf16x8 af[4], bfv[4];                                                   \
    _Pragma("unroll") for (int m = 0; m < 4; ++m)                           \
        af[m] = *(const bf16x8*)(&As[b][(wr * 64 + m * 16 + fr) * 32 + kg]);\
    _Pragma("unroll") for (int n = 0; n < 4; ++n)                           \
        bfv[n] = *(const bf16x8*)(&Bs[b][(wc * 64 + n * 16 + fr) * 32 + kg]);\
    _Pragma("unroll") for (int m = 0; m < 4; ++m)                           \
        _Pragma("unroll") for (int n = 0; n < 4; ++n)                       \
            acc[m][n] = __builtin_amdgcn_mfma_f32_16x16x32_bf16(            \
                af[m], bfv[n], acc[m][n], 0, 0, 0);                         \
  } while (0)

  // prologue: stage tile 0 into buf 0
  STAGE(0, 0);
  __syncthreads();

  for (int kt = 0; kt < NKT; kt += 2) {
    // step A: prefetch kt+1 -> buf1, compute kt from buf0
    if (kt + 1 < NKT) STAGE(1, (kt + 1) * 32);
    COMPUTE(0);
    __syncthreads();  // buf1 ready; buf0 reads done
    // step B: prefetch kt+2 -> buf0, compute kt+1 from buf1
    if (kt + 2 < NKT) STAGE(0, (kt + 2) * 32);
    COMPUTE(1);
    __syncthreads();  // buf0 ready; buf1 reads done
  }
#undef STAGE
#undef COMPUTE

  // epilogue: C/D mapping col = lane&15, row = (lane>>4)*4 + j  [m89/m91]
  const int cr = (lane >> 4) * 4;
  const int cc = lane & 15;
#pragma unroll
  for (int n = 0; n < 4; ++n) {
    const int col = bn0 + wc * 64 + n * 16 + cc;
    const float bv = bias[col];
#pragma unroll
    for (int m = 0; m < 4; ++m) {
      const size_t row = am0 + wr * 64 + m * 16 + cr;
#pragma unroll
      for (int j = 0; j < 4; ++j) {
        const float v = acc[m][n][j] + bv;
        const size_t off = (row + j) * N + col;
        if constexpr (GELU) {
          zout[off] = __float2bfloat16(gelu_tanh(v));
        } else {
          fout[off] = fout[off] + v;  // += x2 residual (in-place on d_out)
        }
      }
    }
  }
}

extern "C" void kernel_launch(void* const* d_in, const int* in_sizes, int n_in,
                              void* d_out, int out_size, void* d_ws,
                              size_t ws_size, hipStream_t stream) {
  const float* x = (const float*)d_in[0];
  const float* n1g = (const float*)d_in[1];
  const float* n1b = (const float*)d_in[2];
  const float* wsp = (const float*)d_in[3];
  const float* n2g = (const float*)d_in[4];
  const float* n2b = (const float*)d_in[5];
  const float* w1 = (const float*)d_in[6];
  const float* b1 = (const float*)d_in[7];
  const float* w2 = (const float*)d_in[8];
  const float* b2 = (const float*)d_in[9];
  float* out = (float*)d_out;

  // ws layout (bf16): y[M*512] | z[M*2048] | w1t[2048*512] | w2t[512*2048]
  __hip_bfloat16* ybuf = (__hip_bfloat16*)d_ws;
  __hip_bfloat16* zbuf = ybuf + (size_t)MROWS * CDIM;
  __hip_bfloat16* w1t = zbuf + (size_t)MROWS * HID;
  __hip_bfloat16* w2t = w1t + (size_t)CDIM * HID;

  cvt_t<CDIM><<<(CDIM * HID) / 256, 256, 0, stream>>>(w1, w1t, HID);
  cvt_t<HID><<<(CDIM * HID) / 256, 256, 0, stream>>>(w2, w2t, CDIM);
  fused_pre<<<2048, 256, 0, stream>>>(x, n1g, n1b, wsp, n2g, n2b, out, ybuf);
  // grids: 784*16 = 12544 and 784*4 = 3136, both % 8 == 0
  gemm_bt<CDIM, HID, true><<<(MROWS / 128) * (HID / 128), 256, 0, stream>>>(
      ybuf, w1t, b1, zbuf, nullptr);
  gemm_bt<HID, CDIM, false><<<(MROWS / 128) * (CDIM / 128), 256, 0, stream>>>(
      zbuf, w2t, b2, nullptr, out);
}

// Round 4
// 939.263 us; speedup vs baseline: 1.1331x; 1.1331x over previous
//
#include <hip/hip_runtime.h>
#include <hip/hip_bf16.h>

// SwinMLP block, fp32 in/out, bf16 MFMA internals.
// Pipeline:
//   1) cvt_t: w1 -> w1t (bf16, N x K), w2 -> w2t (bf16, N x K)
//   2) fused_pre: LN1 + per-head 32x32 spatial matmul + residual -> x2 (fp32, d_out)
//      + LN2(x2) -> y (bf16, ws)
//   3) gemm8p<512,2048,GELU>: z = gelu(y @ w1 + b1)  (bf16, ws)
//   4) gemm8p<2048,512,RES>:  d_out = x2 + z @ w2 + b2 (in-place residual)
//
// R1: m97 128² structure -> gemms ~450 us each, MfmaUtil 20%
// R2: + T1 XCD swizzle   -> FETCH 919->358 MB, dur flat => latency-bound
// R3: 2-phase dbuf       -> flat. Diagnosis: 184 regs -> 2 blocks/CU; every
//     K-step drains vmcnt(0) at __syncthreads; ~400 cy exposed latency/step.
// R4 (this): 8-wave 256x256 tile, BK=32, 4-slot LDS ring, prefetch distance
//     2 K-tiles, counted s_waitcnt vmcnt(4) + raw s_barrier (T3+T4), setprio
//     around MFMA clusters (T5), XOR-involution k-seg swizzle applied on the
//     global source AND the ds_read side (T2, rule-#21-legal with
//     global_load_lds's linear LDS dest): 8-way -> 2-way bank conflict.

typedef __bf16 bf16x8 __attribute__((ext_vector_type(8)));
typedef float f32x4 __attribute__((ext_vector_type(4)));

constexpr int CDIM = 512;
constexpr int HID = 2048;
constexpr int MROWS = 32 * 3136;  // 100352 = 392 * 256
constexpr float LN_EPS = 1e-5f;

static __device__ __forceinline__ float gelu_tanh(float x) {
  const float u = 0.7978845608028654f * fmaf(0.044715f * x * x, x, x);
  const float e = __expf(2.0f * u);
  return 0.5f * x * (2.0f - 2.0f / (e + 1.0f));
}

static __device__ __forceinline__ void load_lds16(const void* g, void* l) {
  // 16B/lane; LDS dest = wave-uniform base + lane*16 (linear, unswizzled)
  __builtin_amdgcn_global_load_lds((__attribute__((address_space(1))) void*)g,
                                   (__attribute__((address_space(3))) void*)l,
                                   16, 0, 0);
}

// ---------------- weight transpose + bf16 convert ----------------
template <int KD>
__global__ __launch_bounds__(256) void cvt_t(const float* __restrict__ src,
                                             __hip_bfloat16* __restrict__ dst,
                                             int ND) {
  const int i = blockIdx.x * 256 + threadIdx.x;
  const int n = i / KD;
  const int k = i - n * KD;
  dst[i] = __float2bfloat16(src[(size_t)k * ND + n]);
}

// ---------------- fused LN1 + spatial mix + residual + LN2 ----------------
__global__ __launch_bounds__(256) void fused_pre(
    const float* __restrict__ x, const float* __restrict__ g1,
    const float* __restrict__ b1, const float* __restrict__ wsp,
    const float* __restrict__ g2, const float* __restrict__ b2,
    float* __restrict__ x2out, __hip_bfloat16* __restrict__ yout) {
  __shared__ float lnbuf[CDIM];
  __shared__ float red[8];

  const int t = threadIdx.x;
  const int lane = t & 63;
  const int w = t >> 6;
  const int c0 = t, c1 = t + 256;
  const int hd0 = c0 >> 5, e0 = c0 & 31;
  const int hd1 = c1 >> 5, e1 = c1 & 31;

  float wc0[32], wc1[32];
#pragma unroll
  for (int d = 0; d < 32; ++d) {
    wc0[d] = wsp[(hd0 * 32 + d) * 32 + e0];
    wc1[d] = wsp[(hd1 * 32 + d) * 32 + e1];
  }
  const float g1v0 = g1[c0], g1v1 = g1[c1], b1v0 = b1[c0], b1v1 = b1[c1];
  const float g2v0 = g2[c0], g2v1 = g2[c1], b2v0 = b2[c0], b2v1 = b2[c1];

  for (int r = blockIdx.x; r < MROWS; r += gridDim.x) {
    const float* xr = x + (size_t)r * CDIM;
    const float xv0 = xr[c0], xv1 = xr[c1];

    float s = xv0 + xv1, ss = xv0 * xv0 + xv1 * xv1;
#pragma unroll
    for (int off = 32; off; off >>= 1) {
      s += __shfl_down(s, off);
      ss += __shfl_down(ss, off);
    }
    if (lane == 0) { red[w * 2] = s; red[w * 2 + 1] = ss; }
    __syncthreads();
    s = red[0] + red[2] + red[4] + red[6];
    ss = red[1] + red[3] + red[5] + red[7];
    float mu = s * (1.0f / CDIM);
    float var = ss * (1.0f / CDIM) - mu * mu;
    float rs = rsqrtf(var + LN_EPS);
    lnbuf[c0] = (xv0 - mu) * rs * g1v0 + b1v0;
    lnbuf[c1] = (xv1 - mu) * rs * g1v1 + b1v1;
    __syncthreads();

    float h0 = 0.f, h1 = 0.f;
#pragma unroll
    for (int d = 0; d < 32; ++d) {
      h0 = fmaf(lnbuf[hd0 * 32 + d], wc0[d], h0);
      h1 = fmaf(lnbuf[hd1 * 32 + d], wc1[d], h1);
    }
    const float a0 = xv0 + h0, a1 = xv1 + h1;
    x2out[(size_t)r * CDIM + c0] = a0;
    x2out[(size_t)r * CDIM + c1] = a1;

    s = a0 + a1;
    ss = a0 * a0 + a1 * a1;
#pragma unroll
    for (int off = 32; off; off >>= 1) {
      s += __shfl_down(s, off);
      ss += __shfl_down(ss, off);
    }
    if (lane == 0) { red[w * 2] = s; red[w * 2 + 1] = ss; }
    __syncthreads();
    s = red[0] + red[2] + red[4] + red[6];
    ss = red[1] + red[3] + red[5] + red[7];
    mu = s * (1.0f / CDIM);
    var = ss * (1.0f / CDIM) - mu * mu;
    rs = rsqrtf(var + LN_EPS);
    yout[(size_t)r * CDIM + c0] = __float2bfloat16((a0 - mu) * rs * g2v0 + b2v0);
    yout[(size_t)r * CDIM + c1] = __float2bfloat16((a1 - mu) * rs * g2v1 + b2v1);
    __syncthreads();
  }
}

// ------- 8-wave 256x256 MFMA GEMM, counted-vmcnt ring pipeline -------
// C(MxN) = A(MxK) * Bt(NxK)^T.  BK=32; LDS = 4 slots x {A 16KB, B 16KB}.
// Prefetch distance 2 K-tiles; boundary wait vmcnt(4) (= tile t+1's loads
// still in flight) certifies tile t complete; barrier makes it block-wide.
// XOR swizzle: seg s holds k-seg (s&3)^((s>>2)&3)^((s>>4)&3) of row s>>2;
// read side applies the same involution (lane-static) -> 2-way conflicts.
template <int K, int N, bool GELU>
__global__ __launch_bounds__(512, 2) void gemm8p(
    const __hip_bfloat16* __restrict__ A, const __hip_bfloat16* __restrict__ Bt,
    const float* __restrict__ bias, __hip_bfloat16* __restrict__ zout,
    float* __restrict__ fout) {
  constexpr int NT = N / 256;
  constexpr int NKT = K / 32;
  __shared__ __attribute__((aligned(16))) __hip_bfloat16 lds[4][2][256 * 32];

  const int tid = threadIdx.x;
  const int lane = tid & 63;
  const int w = tid >> 6;          // 0..7
  const int wm = w >> 2, wn = w & 3;  // 2M x 4N wave grid; wave owns 128x64

  // T1: XCD-aware bijective swizzle (grid % 8 == 0 by construction)
  const int cpx = gridDim.x >> 3;
  const int bid = (blockIdx.x & 7) * cpx + (blockIdx.x >> 3);
  const int tm = bid / NT, tn = bid - tm * NT;
  const size_t am0 = (size_t)tm * 256;
  const int bn0 = tn * 256;

  // staging: thread stages segs tid and tid+512 of each 256x32 tile.
  // row = s>>2; source k-seg pre-swizzled so linear LDS == swizzled layout.
  const int r0 = tid >> 2;
  const int ks0 = (tid & 3) ^ ((tid >> 2) & 3) ^ ((tid >> 4) & 3);
  const __hip_bfloat16* aP0 = A + (am0 + r0) * K + ks0 * 8;
  const __hip_bfloat16* aP1 = aP0 + (size_t)128 * K;  // seg tid+512: row+128, same k-seg
  const __hip_bfloat16* bP0 = Bt + (size_t)(bn0 + r0) * K + ks0 * 8;
  const __hip_bfloat16* bP1 = bP0 + (size_t)128 * K;
  const int lo0 = (w * 64) * 8;        // LDS elem offset, lane*16B within
  const int lo1 = (512 + w * 64) * 8;

#define STAGE_A(sl, kt)                            \
  do {                                             \
    load_lds16(aP0 + (kt) * 32, &lds[sl][0][lo0]); \
    load_lds16(aP1 + (kt) * 32, &lds[sl][0][lo1]); \
  } while (0)
#define STAGE_B(sl, kt)                            \
  do {                                             \
    load_lds16(bP0 + (kt) * 32, &lds[sl][1][lo0]); \
    load_lds16(bP1 + (kt) * 32, &lds[sl][1][lo1]); \
  } while (0)

  f32x4 acc[8][4] = {};
  const int fr = lane & 15;
  // read swizzle (lane-static since row-bases are multiples of 16):
  const int kgs = (((lane >> 4) ^ (lane & 3) ^ ((lane >> 2) & 3))) * 8;

  // prologue: tiles 0,1 -> slots 0,1 (8 loads in flight)
  STAGE_A(0, 0);
  STAGE_B(0, 0);
  STAGE_A(1, 1);
  STAGE_B(1, 1);

  for (int t = 0; t < NKT; ++t) {
    // boundary: certify tile t resident (tile t+1's 4 loads may stay in flight)
    if (t + 1 < NKT)
      asm volatile("s_waitcnt vmcnt(4)" ::: "memory");
    else
      asm volatile("s_waitcnt vmcnt(0)" ::: "memory");
    __builtin_amdgcn_s_barrier();

    const int sl = t & 3;
    const int s2 = (t + 2) & 3;
    const bool pf = (t + 2) < NKT;
    const __hip_bfloat16* As = lds[sl][0];
    const __hip_bfloat16* Bs = lds[sl][1];

    // ---- phase 0: issue A-stage(t+2); compute m=0..3 x all n ----
    if (pf) STAGE_A(s2, t + 2);
    bf16x8 bfv[4];
#pragma unroll
    for (int n = 0; n < 4; ++n)
      bfv[n] = *(const bf16x8*)(Bs + (wn * 64 + n * 16 + fr) * 32 + kgs);
    bf16x8 af[4];
#pragma unroll
    for (int m = 0; m < 4; ++m)
      af[m] = *(const bf16x8*)(As + (wm * 128 + m * 16 + fr) * 32 + kgs);
    __builtin_amdgcn_s_setprio(1);
#pragma unroll
    for (int m = 0; m < 4; ++m)
#pragma unroll
      for (int n = 0; n < 4; ++n)
        acc[m][n] = __builtin_amdgcn_mfma_f32_16x16x32_bf16(af[m], bfv[n],
                                                            acc[m][n], 0, 0, 0);
    __builtin_amdgcn_s_setprio(0);
    __builtin_amdgcn_s_barrier();

    // ---- phase 1: issue B-stage(t+2); compute m=4..7 (reuse bfv) ----
    if (pf) STAGE_B(s2, t + 2);
#pragma unroll
    for (int m = 0; m < 4; ++m)
      af[m] = *(const bf16x8*)(As + (wm * 128 + (m + 4) * 16 + fr) * 32 + kgs);
    __builtin_amdgcn_s_setprio(1);
#pragma unroll
    for (int m = 0; m < 4; ++m)
#pragma unroll
      for (int n = 0; n < 4; ++n)
        acc[m + 4][n] = __builtin_amdgcn_mfma_f32_16x16x32_bf16(
            af[m], bfv[n], acc[m + 4][n], 0, 0, 0);
    __builtin_amdgcn_s_setprio(0);
  }
#undef STAGE_A
#undef STAGE_B

  // epilogue: C/D map col = lane&15, row = (lane>>4)*4 + j  [m89/m91]
  const int cr = (lane >> 4) * 4;
  const int cc = lane & 15;
#pragma unroll
  for (int n = 0; n < 4; ++n) {
    const int col = bn0 + wn * 64 + n * 16 + cc;
    const float bv = bias[col];
#pragma unroll
    for (int m = 0; m < 8; ++m) {
      const size_t row = am0 + wm * 128 + m * 16 + cr;
#pragma unroll
      for (int j = 0; j < 4; ++j) {
        const float v = acc[m][n][j] + bv;
        const size_t off = (row + j) * N + col;
        if constexpr (GELU) {
          zout[off] = __float2bfloat16(gelu_tanh(v));
        } else {
          fout[off] = fout[off] + v;  // += x2 residual (in-place on d_out)
        }
      }
    }
  }
}

extern "C" void kernel_launch(void* const* d_in, const int* in_sizes, int n_in,
                              void* d_out, int out_size, void* d_ws,
                              size_t ws_size, hipStream_t stream) {
  const float* x = (const float*)d_in[0];
  const float* n1g = (const float*)d_in[1];
  const float* n1b = (const float*)d_in[2];
  const float* wsp = (const float*)d_in[3];
  const float* n2g = (const float*)d_in[4];
  const float* n2b = (const float*)d_in[5];
  const float* w1 = (const float*)d_in[6];
  const float* b1 = (const float*)d_in[7];
  const float* w2 = (const float*)d_in[8];
  const float* b2 = (const float*)d_in[9];
  float* out = (float*)d_out;

  // ws layout (bf16): y[M*512] | z[M*2048] | w1t[2048*512] | w2t[512*2048]
  __hip_bfloat16* ybuf = (__hip_bfloat16*)d_ws;
  __hip_bfloat16* zbuf = ybuf + (size_t)MROWS * CDIM;
  __hip_bfloat16* w1t = zbuf + (size_t)MROWS * HID;
  __hip_bfloat16* w2t = w1t + (size_t)CDIM * HID;

  cvt_t<CDIM><<<(CDIM * HID) / 256, 256, 0, stream>>>(w1, w1t, HID);
  cvt_t<HID><<<(CDIM * HID) / 256, 256, 0, stream>>>(w2, w2t, CDIM);
  fused_pre<<<2048, 256, 0, stream>>>(x, n1g, n1b, wsp, n2g, n2b, out, ybuf);
  // grids: 392*8 = 3136 and 392*2 = 784, both % 8 == 0
  gemm8p<CDIM, HID, true><<<(MROWS / 256) * (HID / 256), 512, 0, stream>>>(
      ybuf, w1t, b1, zbuf, nullptr);
  gemm8p<HID, CDIM, false><<<(MROWS / 256) * (CDIM / 256), 512, 0, stream>>>(
      zbuf, w2t, b2, nullptr, out);
}